// Round 10
// baseline (241.928 us; speedup 1.0000x reference)
//
#include <hip/hip_runtime.h>

// CapsuleLayer dynamic routing on MI355X — round 10.
// x: [128, 2048, 8] f32, W: [2048, 32, 8, 16] f32, out v: [128, 32, 16] f32.
// R9 diagnosis: R=8 demanded ~224 VGPR, allocator gave 132 -> hidden L2-resident
// spill + grid 512 capped residency. R10: R=4 (demand ~140, no spill), grid 1024
// (bt 8 x nsup 128), launch_bounds(256,3) caps alloc at 168. Streaming from
// transposed Wt (coalesced), no LDS, no barriers. Tiers: T1 stream, T2 R6 LDS, T3 atomic.

constexpr int NC = 2048;   // in_caps
constexpr int OC = 32;     // out_caps
constexpr int OD = 16;     // out_dim

typedef const __attribute__((address_space(1))) void* gas1_t;
typedef __attribute__((address_space(3))) void* las3_t;

__device__ __forceinline__ void gld16(const void* g, void* l) {
    __builtin_amdgcn_global_load_lds((gas1_t)g, (las3_t)l, 16, 0, 0);
}

#define MEMFENCE() asm volatile("" ::: "memory")
#define BAR() do { MEMFENCE(); __builtin_amdgcn_s_barrier(); MEMFENCE(); } while (0)

// ---------------- T1: W transpose ----------------
// Wt float4 unit: n*1024 + (i*4 + dq)*32 + o   (dq = d-quad)
// src float4 unit: n*1024 + o*32 + i*4 + dq
__global__ __launch_bounds__(256)
void transpose_W(const float* __restrict__ Wg, float* __restrict__ Wtg)
{
    const float4* W4  = (const float4*)Wg;
    float4* Wt4 = (float4*)Wtg;
    const int n = blockIdx.x;
    const int tid = threadIdx.x;
#pragma unroll
    for (int j = 0; j < 4; ++j) {
        const int L  = j * 256 + tid;          // = i*128 + dq*32 + o
        const int o  = L & 31;
        const int dq = (L >> 5) & 3;
        const int i  = L >> 7;
        Wt4[(size_t)n * 1024 + L] = W4[(size_t)n * 1024 + o * 32 + i * 4 + dq];
    }
}

// ---------------- T1: streaming pass, R=4 ----------------
// grid = 1024: bid = bt*128 + nsup (bt 0..7, nsup 0..127). bid%8 = nsup%8 ->
// the 8 bt-siblings of an n-slice share one XCD's L2 (16 slices x 256KB = 4MB).
// 256 threads = 4 independent waves. Wave w: b0 = bt*16 + w*4 (R=4).
// Lane: o = lane&31, h = lane>>5 (d = h*8 + 0..7).
// Per n: x via wave-uniform s_load; W via coalesced global_load_dwordx4 from Wt
// (lane addr (i*4+h*2+qq)*32 + o: contiguous in o).
template<bool FIRST>
__global__ __launch_bounds__(256, 3)
void caps_stream4(const float* __restrict__ xg, const float* __restrict__ Wtg,
                  const float* __restrict__ vin, float* __restrict__ pout)
{
    const int tid  = threadIdx.x;
    const int bid  = blockIdx.x;
    const int bt   = bid >> 7;          // 0..7
    const int nsup = bid & 127;         // 0..127
    const int w    = __builtin_amdgcn_readfirstlane(tid >> 6);
    const int lane = tid & 63;
    const int o    = lane & 31;
    const int h    = lane >> 5;
    const int b0   = bt * 16 + w * 4;
    const int nbase = nsup * 16;

    const float4* Wt4 = (const float4*)Wtg;

    float4 acc[4][2];
#pragma unroll
    for (int r = 0; r < 4; ++r)
#pragma unroll
        for (int qq = 0; qq < 2; ++qq) acc[r][qq] = make_float4(0.f, 0.f, 0.f, 0.f);

    float4 vr[4][2];
    if (!FIRST) {
        const float4* v4 = (const float4*)vin;
#pragma unroll
        for (int r = 0; r < 4; ++r)
#pragma unroll
            for (int qq = 0; qq < 2; ++qq)
                vr[r][qq] = v4[(size_t)(b0 + r) * 128 + o * 4 + h * 2 + qq];
    }

#pragma unroll 1
    for (int t = 0; t < 16; ++t) {
        const int n = nbase + t;

        // x: wave-uniform scalar loads (base + r*64KB + i imm)
        float xs[4][8];
        {
            const float* xb = xg + ((size_t)b0 * NC + n) * 8;
#pragma unroll
            for (int r = 0; r < 4; ++r)
#pragma unroll
                for (int i = 0; i < 8; ++i) xs[r][i] = xb[(size_t)r * NC * 8 + i];
        }

        // lane's W float4 for (i,qq): wn[i*128 + qq*32], contiguous across lanes
        const float4* wn = Wt4 + (size_t)n * 1024 + h * 64 + o;

        float4 u[4][2];
#pragma unroll
        for (int r = 0; r < 4; ++r)
#pragma unroll
            for (int qq = 0; qq < 2; ++qq) u[r][qq] = make_float4(0.f, 0.f, 0.f, 0.f);

        // i-pair ping-pong: 4 float4 in flight per batch
        float4 wA[2][2], wB[2][2];
#pragma unroll
        for (int j = 0; j < 2; ++j)
#pragma unroll
            for (int qq = 0; qq < 2; ++qq) wA[j][qq] = wn[j * 128 + qq * 32];

#pragma unroll
        for (int ip = 0; ip < 4; ++ip) {
            if (ip < 3) {
#pragma unroll
                for (int j = 0; j < 2; ++j)
#pragma unroll
                    for (int qq = 0; qq < 2; ++qq)
                        wB[j][qq] = wn[(ip * 2 + 2 + j) * 128 + qq * 32];
            }
#pragma unroll
            for (int j = 0; j < 2; ++j) {
                const int i = ip * 2 + j;
#pragma unroll
                for (int qq = 0; qq < 2; ++qq) {
                    const float4 wv = wA[j][qq];
#pragma unroll
                    for (int r = 0; r < 4; ++r) {
                        float4* dst = FIRST ? &acc[r][qq] : &u[r][qq];
                        dst->x = fmaf(xs[r][i], wv.x, dst->x);
                        dst->y = fmaf(xs[r][i], wv.y, dst->y);
                        dst->z = fmaf(xs[r][i], wv.z, dst->z);
                        dst->w = fmaf(xs[r][i], wv.w, dst->w);
                    }
                }
            }
#pragma unroll
            for (int j = 0; j < 2; ++j)
#pragma unroll
                for (int qq = 0; qq < 2; ++qq) wA[j][qq] = wB[j][qq];
        }

        if (!FIRST) {
#pragma unroll
            for (int r = 0; r < 4; ++r) {
                float tp = 0.f;
#pragma unroll
                for (int qq = 0; qq < 2; ++qq) {
                    tp = fmaf(u[r][qq].x, vr[r][qq].x, tp);
                    tp = fmaf(u[r][qq].y, vr[r][qq].y, tp);
                    tp = fmaf(u[r][qq].z, vr[r][qq].z, tp);
                    tp = fmaf(u[r][qq].w, vr[r][qq].w, tp);
                }
                const float tt = tp + __shfl_xor(tp, 32);
                // |logit| small -> exp without max-subtract is fp32-safe
                const float e = __expf(tt);
                float Z = e;
                Z += __shfl_xor(Z, 1);
                Z += __shfl_xor(Z, 2);
                Z += __shfl_xor(Z, 4);
                Z += __shfl_xor(Z, 8);
                Z += __shfl_xor(Z, 16);
                const float c = e / Z;
#pragma unroll
                for (int qq = 0; qq < 2; ++qq) {
                    acc[r][qq].x = fmaf(c, u[r][qq].x, acc[r][qq].x);
                    acc[r][qq].y = fmaf(c, u[r][qq].y, acc[r][qq].y);
                    acc[r][qq].z = fmaf(c, u[r][qq].z, acc[r][qq].z);
                    acc[r][qq].w = fmaf(c, u[r][qq].w, acc[r][qq].w);
                }
            }
        }
    }

    // partial store: P4[((nsup*128 + b)*4 + h*2+qq)*32 + o], coalesced
    const float sc = FIRST ? (1.0f / 32.0f) : 1.0f;
    float4* P4 = (float4*)pout;
#pragma unroll
    for (int r = 0; r < 4; ++r) {
        const size_t base = ((size_t)(nsup * 128 + b0 + r) * 4 + h * 2) * 32 + o;
#pragma unroll
        for (int qq = 0; qq < 2; ++qq) {
            float4 v;
            v.x = acc[r][qq].x * sc; v.y = acc[r][qq].y * sc;
            v.z = acc[r][qq].z * sc; v.w = acc[r][qq].w * sc;
            P4[base + (size_t)qq * 32] = v;
        }
    }
}

// ---------------- T2: R6 LDS kernel (proven 73us/pass) ----------------
template<int NR, bool FIRST, bool ATOMIC>
__global__ __launch_bounds__(256)
void caps_pass(const float* __restrict__ xg, const float* __restrict__ Wg,
               const float* __restrict__ vin, float* __restrict__ pout)
{
    __shared__ float4 Wl[2][1024];   // 32 KB ring

    constexpr int NSUPC = 2048 / NR;
    const int tid  = threadIdx.x;
    const int bid  = blockIdx.x;
    const int bt   = bid / NSUPC;
    const int nsup = bid % NSUPC;
    const int w    = __builtin_amdgcn_readfirstlane(tid >> 6);
    const int lane = tid & 63;
    const int o    = lane & 31;
    const int h    = lane >> 5;
    const int sw   = o & 7;
    const int b0   = bt * 16 + w * 4;
    const int nbase = nsup * NR;

    const float4* Wg4 = (const float4*)Wg;

    float4 acc[4][2];
#pragma unroll
    for (int r = 0; r < 4; ++r)
#pragma unroll
        for (int qq = 0; qq < 2; ++qq) acc[r][qq] = make_float4(0.f, 0.f, 0.f, 0.f);

    float4 vr[4][2];
    if (!FIRST) {
        const float4* v4 = (const float4*)vin;
#pragma unroll
        for (int r = 0; r < 4; ++r)
#pragma unroll
            for (int qq = 0; qq < 2; ++qq)
                vr[r][qq] = v4[(size_t)(b0 + r) * 128 + o * 4 + h * 2 + qq];
    }

#pragma unroll
    for (int j = 0; j < 4; ++j) {
        const int L = tid + 256 * j;
        const int oo = L >> 5, cc = L & 31;
        gld16(&Wg4[(size_t)nbase * 1024 + oo * 32 + (cc ^ (oo & 7))], &Wl[0][L]);
    }

#pragma unroll 1
    for (int t = 0; t < NR; ++t) {
        BAR();
        if (t + 1 < NR) {
#pragma unroll
            for (int j = 0; j < 4; ++j) {
                const int L = tid + 256 * j;
                const int oo = L >> 5, cc = L & 31;
                gld16(&Wg4[(size_t)(nbase + t + 1) * 1024 + oo * 32 + (cc ^ (oo & 7))],
                      &Wl[(t + 1) & 1][L]);
            }
            asm volatile("s_waitcnt vmcnt(4)" ::: "memory");
        } else {
            asm volatile("s_waitcnt vmcnt(0)" ::: "memory");
        }
        BAR();

        const int n = nbase + t;
        float xs[4][8];
#pragma unroll
        for (int r = 0; r < 4; ++r) {
            const float* xp = xg + ((size_t)(b0 + r) * NC + n) * 8;
#pragma unroll
            for (int i = 0; i < 8; ++i) xs[r][i] = xp[i];
        }
        const float4* wrow = &Wl[t & 1][o * 32];

        __builtin_amdgcn_s_setprio(1);
        if (FIRST) {
#pragma unroll
            for (int i = 0; i < 8; ++i)
#pragma unroll
                for (int qq = 0; qq < 2; ++qq) {
                    const float4 wv = wrow[(i * 4 + h * 2 + qq) ^ sw];
#pragma unroll
                    for (int r = 0; r < 4; ++r) {
                        acc[r][qq].x = fmaf(xs[r][i], wv.x, acc[r][qq].x);
                        acc[r][qq].y = fmaf(xs[r][i], wv.y, acc[r][qq].y);
                        acc[r][qq].z = fmaf(xs[r][i], wv.z, acc[r][qq].z);
                        acc[r][qq].w = fmaf(xs[r][i], wv.w, acc[r][qq].w);
                    }
                }
        } else {
            float4 u[4][2];
#pragma unroll
            for (int r = 0; r < 4; ++r)
#pragma unroll
                for (int qq = 0; qq < 2; ++qq) u[r][qq] = make_float4(0.f, 0.f, 0.f, 0.f);
#pragma unroll
            for (int i = 0; i < 8; ++i)
#pragma unroll
                for (int qq = 0; qq < 2; ++qq) {
                    const float4 wv = wrow[(i * 4 + h * 2 + qq) ^ sw];
#pragma unroll
                    for (int r = 0; r < 4; ++r) {
                        u[r][qq].x = fmaf(xs[r][i], wv.x, u[r][qq].x);
                        u[r][qq].y = fmaf(xs[r][i], wv.y, u[r][qq].y);
                        u[r][qq].z = fmaf(xs[r][i], wv.z, u[r][qq].z);
                        u[r][qq].w = fmaf(xs[r][i], wv.w, u[r][qq].w);
                    }
                }
#pragma unroll
            for (int r = 0; r < 4; ++r) {
                float tp = 0.f;
#pragma unroll
                for (int qq = 0; qq < 2; ++qq) {
                    tp = fmaf(u[r][qq].x, vr[r][qq].x, tp);
                    tp = fmaf(u[r][qq].y, vr[r][qq].y, tp);
                    tp = fmaf(u[r][qq].z, vr[r][qq].z, tp);
                    tp = fmaf(u[r][qq].w, vr[r][qq].w, tp);
                }
                const float tt = tp + __shfl_xor(tp, 32);
                const float e = __expf(tt);
                float Z = e;
                Z += __shfl_xor(Z, 1);
                Z += __shfl_xor(Z, 2);
                Z += __shfl_xor(Z, 4);
                Z += __shfl_xor(Z, 8);
                Z += __shfl_xor(Z, 16);
                const float c = e / Z;
#pragma unroll
                for (int qq = 0; qq < 2; ++qq) {
                    acc[r][qq].x = fmaf(c, u[r][qq].x, acc[r][qq].x);
                    acc[r][qq].y = fmaf(c, u[r][qq].y, acc[r][qq].y);
                    acc[r][qq].z = fmaf(c, u[r][qq].z, acc[r][qq].z);
                    acc[r][qq].w = fmaf(c, u[r][qq].w, acc[r][qq].w);
                }
            }
        }
        __builtin_amdgcn_s_setprio(0);
    }

    const float sc = FIRST ? (1.0f / 32.0f) : 1.0f;
    if (ATOMIC) {
#pragma unroll
        for (int r = 0; r < 4; ++r) {
            float* sb = pout + (size_t)(b0 + r) * (OC * OD) + o * OD + h * 8;
#pragma unroll
            for (int qq = 0; qq < 2; ++qq) {
                atomicAdd(sb + qq * 4 + 0, acc[r][qq].x * sc);
                atomicAdd(sb + qq * 4 + 1, acc[r][qq].y * sc);
                atomicAdd(sb + qq * 4 + 2, acc[r][qq].z * sc);
                atomicAdd(sb + qq * 4 + 3, acc[r][qq].w * sc);
            }
        }
    } else {
        float4* P4 = (float4*)pout;
#pragma unroll
        for (int r = 0; r < 4; ++r) {
            const size_t base = ((size_t)(nsup * 128 + b0 + r) * 4 + h * 2) * 32 + o;
#pragma unroll
            for (int qq = 0; qq < 2; ++qq) {
                float4 v;
                v.x = acc[r][qq].x * sc; v.y = acc[r][qq].y * sc;
                v.z = acc[r][qq].z * sc; v.w = acc[r][qq].w * sc;
                P4[base + (size_t)qq * 32] = v;
            }
        }
    }
}

// Fused reduce (over NS nsup partials) + squash. grid 64 x 256. PROVEN.
template<int NS>
__global__ void reduce_squash(const float* __restrict__ P, const float* __restrict__ vprev,
                              float* __restrict__ vout)
{
    __shared__ float sqb[256];
    const int tid = threadIdx.x;
    const int blk = blockIdx.x;
    const float4* P4 = (const float4*)P;

    float4 a = make_float4(0.f, 0.f, 0.f, 0.f);
#pragma unroll 8
    for (int ns = 0; ns < NS; ++ns) {
        const float4 p = P4[(size_t)ns * 16384 + blk * 256 + tid];
        a.x += p.x; a.y += p.y; a.z += p.z; a.w += p.w;
    }
    sqb[tid] = a.x * a.x + a.y * a.y + a.z * a.z + a.w * a.w;
    __syncthreads();
    const int base = tid & 0x9F;   // clear hq bits (5,6)
    const float sq = sqb[base] + sqb[base + 32] + sqb[base + 64] + sqb[base + 96];
    const float f = sq / ((1.0f + sq) * sqrtf(sq + 1e-8f));

    const int b  = blk * 2 + (tid >> 7);
    const int hq = (tid >> 5) & 3;
    const int o  = tid & 31;
    const size_t unit = (size_t)(b * 32 + o) * 4 + hq;
    float4 r;
    r.x = a.x * f; r.y = a.y * f; r.z = a.z * f; r.w = a.w * f;
    if (vprev) {
        const float4 p = ((const float4*)vprev)[unit];
        r.x += p.x; r.y += p.y; r.z += p.z; r.w += p.w;
    }
    ((float4*)vout)[unit] = r;
}

// atomic-path squash
__global__ void squash_k(const float* __restrict__ s, const float* __restrict__ vprev,
                         float* __restrict__ vout)
{
    const int row = blockIdx.x * blockDim.x + threadIdx.x;
    if (row >= 128 * 32) return;
    const float4* s4 = (const float4*)s;
    float4 t[4];
    float sq = 0.f;
#pragma unroll
    for (int q = 0; q < 4; ++q) {
        t[q] = s4[row * 4 + q];
        sq += t[q].x * t[q].x + t[q].y * t[q].y + t[q].z * t[q].z + t[q].w * t[q].w;
    }
    const float f = sq / ((1.0f + sq) * sqrtf(sq + 1e-8f));
    float4* o4 = (float4*)vout;
#pragma unroll
    for (int q = 0; q < 4; ++q) {
        float4 r;
        r.x = t[q].x * f; r.y = t[q].y * f; r.z = t[q].z * f; r.w = t[q].w * f;
        if (vprev) {
            const float4 p = ((const float4*)vprev)[row * 4 + q];
            r.x += p.x; r.y += p.y; r.z += p.z; r.w += p.w;
        }
        o4[row * 4 + q] = r;
    }
}

extern "C" void kernel_launch(void* const* d_in, const int* in_sizes, int n_in,
                              void* d_out, int out_size, void* d_ws, size_t ws_size,
                              hipStream_t stream)
{
    const float* x = (const float*)d_in[0];
    const float* W = (const float*)d_in[1];
    float* out = (float*)d_out;

    const size_t WT = (size_t)2048 * 32 * 128;        // 8.39M floats = 33.55 MB
    const size_t P1 = (size_t)128 * 128 * 512;        // 8.39M floats = 33.55 MB
    const size_t NEED1 = (WT + P1 + 2 * 65536) * sizeof(float);   // ~67.6 MB
    const size_t NEED2 = (P1 + 2 * 65536) * sizeof(float);        // ~34.1 MB

    if (ws_size >= NEED1) {
        // T1: transpose + pure streaming (no LDS, no barriers), R=4, grid 1024
        float* Wt = (float*)d_ws;
        float* P  = Wt + WT;
        float* v0 = P + P1;
        float* vs = v0 + 65536;

        transpose_W<<<dim3(2048), dim3(256), 0, stream>>>(W, Wt);

        caps_stream4<true><<<dim3(1024), dim3(256), 0, stream>>>(x, Wt, nullptr, P);
        reduce_squash<128><<<dim3(64), dim3(256), 0, stream>>>(P, nullptr, v0);

        caps_stream4<false><<<dim3(1024), dim3(256), 0, stream>>>(x, Wt, v0, P);
        reduce_squash<128><<<dim3(64), dim3(256), 0, stream>>>(P, v0, vs);   // vs = v0+v1

        caps_stream4<false><<<dim3(1024), dim3(256), 0, stream>>>(x, Wt, vs, P);
        reduce_squash<128><<<dim3(64), dim3(256), 0, stream>>>(P, nullptr, out);
    } else if (ws_size >= NEED2) {
        // T2: proven R6 LDS path
        float* P  = (float*)d_ws;
        float* v0 = P + P1;
        float* vs = v0 + 65536;

        caps_pass<16, true, false><<<dim3(1024), dim3(256), 0, stream>>>(x, W, nullptr, P);
        reduce_squash<128><<<dim3(64), dim3(256), 0, stream>>>(P, nullptr, v0);

        caps_pass<16, false, false><<<dim3(1024), dim3(256), 0, stream>>>(x, W, v0, P);
        reduce_squash<128><<<dim3(64), dim3(256), 0, stream>>>(P, v0, vs);

        caps_pass<16, false, false><<<dim3(1024), dim3(256), 0, stream>>>(x, W, vs, P);
        reduce_squash<128><<<dim3(64), dim3(256), 0, stream>>>(P, nullptr, out);
    } else {
        // T3: atomic fallback
        float* s  = (float*)d_ws;
        float* v0 = s + 65536;
        float* vs = v0 + 65536;
        const size_t sbytes = (size_t)65536 * sizeof(float);

        hipMemsetAsync(s, 0, sbytes, stream);
        caps_pass<16, true, true><<<dim3(1024), dim3(256), 0, stream>>>(x, W, nullptr, s);
        squash_k<<<dim3(16), dim3(256), 0, stream>>>(s, nullptr, v0);

        hipMemsetAsync(s, 0, sbytes, stream);
        caps_pass<16, false, true><<<dim3(1024), dim3(256), 0, stream>>>(x, W, v0, s);
        squash_k<<<dim3(16), dim3(256), 0, stream>>>(s, v0, vs);

        hipMemsetAsync(s, 0, sbytes, stream);
        caps_pass<16, false, true><<<dim3(1024), dim3(256), 0, stream>>>(x, W, vs, s);
        squash_k<<<dim3(16), dim3(256), 0, stream>>>(s, nullptr, out);
    }
}

// Round 11
// 188.405 us; speedup vs baseline: 1.2841x; 1.2841x over previous
//
#include <hip/hip_runtime.h>

// CapsuleLayer dynamic routing on MI355X — round 11.
// x: [128, 2048, 8] f32, W: [2048, 32, 8, 16] f32, out v: [128, 32, 16] f32.
// R10 diagnosis: launch_bounds(256,3) is only a MINIMUM -> allocator sandbagged
// to 64 VGPR (8-waves/EU heuristic) and spilled the ~146-VGPR-demand kernel.
// R11 = R10 with ONE change: amdgpu_waves_per_eu(3,3) pins the allocation
// budget (<=170) so the kernel runs spill-free at 3 waves/EU.

constexpr int NC = 2048;   // in_caps
constexpr int OC = 32;     // out_caps
constexpr int OD = 16;     // out_dim

typedef const __attribute__((address_space(1))) void* gas1_t;
typedef __attribute__((address_space(3))) void* las3_t;

__device__ __forceinline__ void gld16(const void* g, void* l) {
    __builtin_amdgcn_global_load_lds((gas1_t)g, (las3_t)l, 16, 0, 0);
}

#define MEMFENCE() asm volatile("" ::: "memory")
#define BAR() do { MEMFENCE(); __builtin_amdgcn_s_barrier(); MEMFENCE(); } while (0)

// ---------------- T1: W transpose ----------------
// Wt float4 unit: n*1024 + (i*4 + dq)*32 + o   (dq = d-quad)
// src float4 unit: n*1024 + o*32 + i*4 + dq
__global__ __launch_bounds__(256)
void transpose_W(const float* __restrict__ Wg, float* __restrict__ Wtg)
{
    const float4* W4  = (const float4*)Wg;
    float4* Wt4 = (float4*)Wtg;
    const int n = blockIdx.x;
    const int tid = threadIdx.x;
#pragma unroll
    for (int j = 0; j < 4; ++j) {
        const int L  = j * 256 + tid;          // = i*128 + dq*32 + o
        const int o  = L & 31;
        const int dq = (L >> 5) & 3;
        const int i  = L >> 7;
        Wt4[(size_t)n * 1024 + L] = W4[(size_t)n * 1024 + o * 32 + i * 4 + dq];
    }
}

// ---------------- T1: streaming pass, R=4, pinned 3 waves/EU ----------------
// grid = 1024: bid = bt*128 + nsup (bt 0..7, nsup 0..127). bid%8 = nsup%8 ->
// the 8 bt-siblings of an n-slice share one XCD's L2 (16 slices x 256KB = 4MB).
// 256 threads = 4 independent waves reading the SAME n-stream (intra-block
// 4-wave redundancy intended to be absorbed by L1). Wave w: b0 = bt*16 + w*4.
// Lane: o = lane&31, h = lane>>5 (d = h*8 + 0..7).
// Per n: x via wave-uniform s_load; W via coalesced global_load_dwordx4 from Wt
// (lane addr (i*4+h*2+qq)*32 + o: contiguous in o), 2-deep i-pair ping-pong.
template<bool FIRST>
__global__ __launch_bounds__(256)
__attribute__((amdgpu_waves_per_eu(3, 3)))
void caps_stream4(const float* __restrict__ xg, const float* __restrict__ Wtg,
                  const float* __restrict__ vin, float* __restrict__ pout)
{
    const int tid  = threadIdx.x;
    const int bid  = blockIdx.x;
    const int bt   = bid >> 7;          // 0..7
    const int nsup = bid & 127;         // 0..127
    const int w    = __builtin_amdgcn_readfirstlane(tid >> 6);
    const int lane = tid & 63;
    const int o    = lane & 31;
    const int h    = lane >> 5;
    const int b0   = bt * 16 + w * 4;
    const int nbase = nsup * 16;

    const float4* Wt4 = (const float4*)Wtg;

    float4 acc[4][2];
#pragma unroll
    for (int r = 0; r < 4; ++r)
#pragma unroll
        for (int qq = 0; qq < 2; ++qq) acc[r][qq] = make_float4(0.f, 0.f, 0.f, 0.f);

    float4 vr[4][2];
    if (!FIRST) {
        const float4* v4 = (const float4*)vin;
#pragma unroll
        for (int r = 0; r < 4; ++r)
#pragma unroll
            for (int qq = 0; qq < 2; ++qq)
                vr[r][qq] = v4[(size_t)(b0 + r) * 128 + o * 4 + h * 2 + qq];
    }

#pragma unroll 1
    for (int t = 0; t < 16; ++t) {
        const int n = nbase + t;

        // x: wave-uniform scalar loads (base + r*64KB + i imm) -> SGPRs
        float xs[4][8];
        {
            const float* xb = xg + ((size_t)b0 * NC + n) * 8;
#pragma unroll
            for (int r = 0; r < 4; ++r)
#pragma unroll
                for (int i = 0; i < 8; ++i) xs[r][i] = xb[(size_t)r * NC * 8 + i];
        }

        // lane's W float4 for (i,qq): wn[i*128 + qq*32], contiguous across lanes
        const float4* wn = Wt4 + (size_t)n * 1024 + h * 64 + o;

        float4 u[4][2];
#pragma unroll
        for (int r = 0; r < 4; ++r)
#pragma unroll
            for (int qq = 0; qq < 2; ++qq) u[r][qq] = make_float4(0.f, 0.f, 0.f, 0.f);

        // i-pair ping-pong: 4 float4 in flight per batch
        float4 wA[2][2], wB[2][2];
#pragma unroll
        for (int j = 0; j < 2; ++j)
#pragma unroll
            for (int qq = 0; qq < 2; ++qq) wA[j][qq] = wn[j * 128 + qq * 32];

#pragma unroll
        for (int ip = 0; ip < 4; ++ip) {
            if (ip < 3) {
#pragma unroll
                for (int j = 0; j < 2; ++j)
#pragma unroll
                    for (int qq = 0; qq < 2; ++qq)
                        wB[j][qq] = wn[(ip * 2 + 2 + j) * 128 + qq * 32];
            }
#pragma unroll
            for (int j = 0; j < 2; ++j) {
                const int i = ip * 2 + j;
#pragma unroll
                for (int qq = 0; qq < 2; ++qq) {
                    const float4 wv = wA[j][qq];
#pragma unroll
                    for (int r = 0; r < 4; ++r) {
                        float4* dst = FIRST ? &acc[r][qq] : &u[r][qq];
                        dst->x = fmaf(xs[r][i], wv.x, dst->x);
                        dst->y = fmaf(xs[r][i], wv.y, dst->y);
                        dst->z = fmaf(xs[r][i], wv.z, dst->z);
                        dst->w = fmaf(xs[r][i], wv.w, dst->w);
                    }
                }
            }
#pragma unroll
            for (int j = 0; j < 2; ++j)
#pragma unroll
                for (int qq = 0; qq < 2; ++qq) wA[j][qq] = wB[j][qq];
        }

        if (!FIRST) {
#pragma unroll
            for (int r = 0; r < 4; ++r) {
                float tp = 0.f;
#pragma unroll
                for (int qq = 0; qq < 2; ++qq) {
                    tp = fmaf(u[r][qq].x, vr[r][qq].x, tp);
                    tp = fmaf(u[r][qq].y, vr[r][qq].y, tp);
                    tp = fmaf(u[r][qq].z, vr[r][qq].z, tp);
                    tp = fmaf(u[r][qq].w, vr[r][qq].w, tp);
                }
                const float tt = tp + __shfl_xor(tp, 32);
                // |logit| small -> exp without max-subtract is fp32-safe
                const float e = __expf(tt);
                float Z = e;
                Z += __shfl_xor(Z, 1);
                Z += __shfl_xor(Z, 2);
                Z += __shfl_xor(Z, 4);
                Z += __shfl_xor(Z, 8);
                Z += __shfl_xor(Z, 16);
                const float c = e / Z;
#pragma unroll
                for (int qq = 0; qq < 2; ++qq) {
                    acc[r][qq].x = fmaf(c, u[r][qq].x, acc[r][qq].x);
                    acc[r][qq].y = fmaf(c, u[r][qq].y, acc[r][qq].y);
                    acc[r][qq].z = fmaf(c, u[r][qq].z, acc[r][qq].z);
                    acc[r][qq].w = fmaf(c, u[r][qq].w, acc[r][qq].w);
                }
            }
        }
    }

    // partial store: P4[((nsup*128 + b)*4 + h*2+qq)*32 + o], coalesced
    const float sc = FIRST ? (1.0f / 32.0f) : 1.0f;
    float4* P4 = (float4*)pout;
#pragma unroll
    for (int r = 0; r < 4; ++r) {
        const size_t base = ((size_t)(nsup * 128 + b0 + r) * 4 + h * 2) * 32 + o;
#pragma unroll
        for (int qq = 0; qq < 2; ++qq) {
            float4 v;
            v.x = acc[r][qq].x * sc; v.y = acc[r][qq].y * sc;
            v.z = acc[r][qq].z * sc; v.w = acc[r][qq].w * sc;
            P4[base + (size_t)qq * 32] = v;
        }
    }
}

// ---------------- T2: R6 LDS kernel (proven 73us/pass) ----------------
template<int NR, bool FIRST, bool ATOMIC>
__global__ __launch_bounds__(256)
void caps_pass(const float* __restrict__ xg, const float* __restrict__ Wg,
               const float* __restrict__ vin, float* __restrict__ pout)
{
    __shared__ float4 Wl[2][1024];   // 32 KB ring

    constexpr int NSUPC = 2048 / NR;
    const int tid  = threadIdx.x;
    const int bid  = blockIdx.x;
    const int bt   = bid / NSUPC;
    const int nsup = bid % NSUPC;
    const int w    = __builtin_amdgcn_readfirstlane(tid >> 6);
    const int lane = tid & 63;
    const int o    = lane & 31;
    const int h    = lane >> 5;
    const int sw   = o & 7;
    const int b0   = bt * 16 + w * 4;
    const int nbase = nsup * NR;

    const float4* Wg4 = (const float4*)Wg;

    float4 acc[4][2];
#pragma unroll
    for (int r = 0; r < 4; ++r)
#pragma unroll
        for (int qq = 0; qq < 2; ++qq) acc[r][qq] = make_float4(0.f, 0.f, 0.f, 0.f);

    float4 vr[4][2];
    if (!FIRST) {
        const float4* v4 = (const float4*)vin;
#pragma unroll
        for (int r = 0; r < 4; ++r)
#pragma unroll
            for (int qq = 0; qq < 2; ++qq)
                vr[r][qq] = v4[(size_t)(b0 + r) * 128 + o * 4 + h * 2 + qq];
    }

#pragma unroll
    for (int j = 0; j < 4; ++j) {
        const int L = tid + 256 * j;
        const int oo = L >> 5, cc = L & 31;
        gld16(&Wg4[(size_t)nbase * 1024 + oo * 32 + (cc ^ (oo & 7))], &Wl[0][L]);
    }

#pragma unroll 1
    for (int t = 0; t < NR; ++t) {
        BAR();
        if (t + 1 < NR) {
#pragma unroll
            for (int j = 0; j < 4; ++j) {
                const int L = tid + 256 * j;
                const int oo = L >> 5, cc = L & 31;
                gld16(&Wg4[(size_t)(nbase + t + 1) * 1024 + oo * 32 + (cc ^ (oo & 7))],
                      &Wl[(t + 1) & 1][L]);
            }
            asm volatile("s_waitcnt vmcnt(4)" ::: "memory");
        } else {
            asm volatile("s_waitcnt vmcnt(0)" ::: "memory");
        }
        BAR();

        const int n = nbase + t;
        float xs[4][8];
#pragma unroll
        for (int r = 0; r < 4; ++r) {
            const float* xp = xg + ((size_t)(b0 + r) * NC + n) * 8;
#pragma unroll
            for (int i = 0; i < 8; ++i) xs[r][i] = xp[i];
        }
        const float4* wrow = &Wl[t & 1][o * 32];

        __builtin_amdgcn_s_setprio(1);
        if (FIRST) {
#pragma unroll
            for (int i = 0; i < 8; ++i)
#pragma unroll
                for (int qq = 0; qq < 2; ++qq) {
                    const float4 wv = wrow[(i * 4 + h * 2 + qq) ^ sw];
#pragma unroll
                    for (int r = 0; r < 4; ++r) {
                        acc[r][qq].x = fmaf(xs[r][i], wv.x, acc[r][qq].x);
                        acc[r][qq].y = fmaf(xs[r][i], wv.y, acc[r][qq].y);
                        acc[r][qq].z = fmaf(xs[r][i], wv.z, acc[r][qq].z);
                        acc[r][qq].w = fmaf(xs[r][i], wv.w, acc[r][qq].w);
                    }
                }
        } else {
            float4 u[4][2];
#pragma unroll
            for (int r = 0; r < 4; ++r)
#pragma unroll
                for (int qq = 0; qq < 2; ++qq) u[r][qq] = make_float4(0.f, 0.f, 0.f, 0.f);
#pragma unroll
            for (int i = 0; i < 8; ++i)
#pragma unroll
                for (int qq = 0; qq < 2; ++qq) {
                    const float4 wv = wrow[(i * 4 + h * 2 + qq) ^ sw];
#pragma unroll
                    for (int r = 0; r < 4; ++r) {
                        u[r][qq].x = fmaf(xs[r][i], wv.x, u[r][qq].x);
                        u[r][qq].y = fmaf(xs[r][i], wv.y, u[r][qq].y);
                        u[r][qq].z = fmaf(xs[r][i], wv.z, u[r][qq].z);
                        u[r][qq].w = fmaf(xs[r][i], wv.w, u[r][qq].w);
                    }
                }
#pragma unroll
            for (int r = 0; r < 4; ++r) {
                float tp = 0.f;
#pragma unroll
                for (int qq = 0; qq < 2; ++qq) {
                    tp = fmaf(u[r][qq].x, vr[r][qq].x, tp);
                    tp = fmaf(u[r][qq].y, vr[r][qq].y, tp);
                    tp = fmaf(u[r][qq].z, vr[r][qq].z, tp);
                    tp = fmaf(u[r][qq].w, vr[r][qq].w, tp);
                }
                const float tt = tp + __shfl_xor(tp, 32);
                const float e = __expf(tt);
                float Z = e;
                Z += __shfl_xor(Z, 1);
                Z += __shfl_xor(Z, 2);
                Z += __shfl_xor(Z, 4);
                Z += __shfl_xor(Z, 8);
                Z += __shfl_xor(Z, 16);
                const float c = e / Z;
#pragma unroll
                for (int qq = 0; qq < 2; ++qq) {
                    acc[r][qq].x = fmaf(c, u[r][qq].x, acc[r][qq].x);
                    acc[r][qq].y = fmaf(c, u[r][qq].y, acc[r][qq].y);
                    acc[r][qq].z = fmaf(c, u[r][qq].z, acc[r][qq].z);
                    acc[r][qq].w = fmaf(c, u[r][qq].w, acc[r][qq].w);
                }
            }
        }
        __builtin_amdgcn_s_setprio(0);
    }

    const float sc = FIRST ? (1.0f / 32.0f) : 1.0f;
    if (ATOMIC) {
#pragma unroll
        for (int r = 0; r < 4; ++r) {
            float* sb = pout + (size_t)(b0 + r) * (OC * OD) + o * OD + h * 8;
#pragma unroll
            for (int qq = 0; qq < 2; ++qq) {
                atomicAdd(sb + qq * 4 + 0, acc[r][qq].x * sc);
                atomicAdd(sb + qq * 4 + 1, acc[r][qq].y * sc);
                atomicAdd(sb + qq * 4 + 2, acc[r][qq].z * sc);
                atomicAdd(sb + qq * 4 + 3, acc[r][qq].w * sc);
            }
        }
    } else {
        float4* P4 = (float4*)pout;
#pragma unroll
        for (int r = 0; r < 4; ++r) {
            const size_t base = ((size_t)(nsup * 128 + b0 + r) * 4 + h * 2) * 32 + o;
#pragma unroll
            for (int qq = 0; qq < 2; ++qq) {
                float4 v;
                v.x = acc[r][qq].x * sc; v.y = acc[r][qq].y * sc;
                v.z = acc[r][qq].z * sc; v.w = acc[r][qq].w * sc;
                P4[base + (size_t)qq * 32] = v;
            }
        }
    }
}

// Fused reduce (over NS nsup partials) + squash. grid 64 x 256. PROVEN.
template<int NS>
__global__ void reduce_squash(const float* __restrict__ P, const float* __restrict__ vprev,
                              float* __restrict__ vout)
{
    __shared__ float sqb[256];
    const int tid = threadIdx.x;
    const int blk = blockIdx.x;
    const float4* P4 = (const float4*)P;

    float4 a = make_float4(0.f, 0.f, 0.f, 0.f);
#pragma unroll 8
    for (int ns = 0; ns < NS; ++ns) {
        const float4 p = P4[(size_t)ns * 16384 + blk * 256 + tid];
        a.x += p.x; a.y += p.y; a.z += p.z; a.w += p.w;
    }
    sqb[tid] = a.x * a.x + a.y * a.y + a.z * a.z + a.w * a.w;
    __syncthreads();
    const int base = tid & 0x9F;   // clear hq bits (5,6)
    const float sq = sqb[base] + sqb[base + 32] + sqb[base + 64] + sqb[base + 96];
    const float f = sq / ((1.0f + sq) * sqrtf(sq + 1e-8f));

    const int b  = blk * 2 + (tid >> 7);
    const int hq = (tid >> 5) & 3;
    const int o  = tid & 31;
    const size_t unit = (size_t)(b * 32 + o) * 4 + hq;
    float4 r;
    r.x = a.x * f; r.y = a.y * f; r.z = a.z * f; r.w = a.w * f;
    if (vprev) {
        const float4 p = ((const float4*)vprev)[unit];
        r.x += p.x; r.y += p.y; r.z += p.z; r.w += p.w;
    }
    ((float4*)vout)[unit] = r;
}

// atomic-path squash
__global__ void squash_k(const float* __restrict__ s, const float* __restrict__ vprev,
                         float* __restrict__ vout)
{
    const int row = blockIdx.x * blockDim.x + threadIdx.x;
    if (row >= 128 * 32) return;
    const float4* s4 = (const float4*)s;
    float4 t[4];
    float sq = 0.f;
#pragma unroll
    for (int q = 0; q < 4; ++q) {
        t[q] = s4[row * 4 + q];
        sq += t[q].x * t[q].x + t[q].y * t[q].y + t[q].z * t[q].z + t[q].w * t[q].w;
    }
    const float f = sq / ((1.0f + sq) * sqrtf(sq + 1e-8f));
    float4* o4 = (float4*)vout;
#pragma unroll
    for (int q = 0; q < 4; ++q) {
        float4 r;
        r.x = t[q].x * f; r.y = t[q].y * f; r.z = t[q].z * f; r.w = t[q].w * f;
        if (vprev) {
            const float4 p = ((const float4*)vprev)[row * 4 + q];
            r.x += p.x; r.y += p.y; r.z += p.z; r.w += p.w;
        }
        o4[row * 4 + q] = r;
    }
}

extern "C" void kernel_launch(void* const* d_in, const int* in_sizes, int n_in,
                              void* d_out, int out_size, void* d_ws, size_t ws_size,
                              hipStream_t stream)
{
    const float* x = (const float*)d_in[0];
    const float* W = (const float*)d_in[1];
    float* out = (float*)d_out;

    const size_t WT = (size_t)2048 * 32 * 128;        // 8.39M floats = 33.55 MB
    const size_t P1 = (size_t)128 * 128 * 512;        // 8.39M floats = 33.55 MB
    const size_t NEED1 = (WT + P1 + 2 * 65536) * sizeof(float);   // ~67.6 MB
    const size_t NEED2 = (P1 + 2 * 65536) * sizeof(float);        // ~34.1 MB

    if (ws_size >= NEED1) {
        // T1: transpose + pure streaming (no LDS, no barriers), R=4, grid 1024
        float* Wt = (float*)d_ws;
        float* P  = Wt + WT;
        float* v0 = P + P1;
        float* vs = v0 + 65536;

        transpose_W<<<dim3(2048), dim3(256), 0, stream>>>(W, Wt);

        caps_stream4<true><<<dim3(1024), dim3(256), 0, stream>>>(x, Wt, nullptr, P);
        reduce_squash<128><<<dim3(64), dim3(256), 0, stream>>>(P, nullptr, v0);

        caps_stream4<false><<<dim3(1024), dim3(256), 0, stream>>>(x, Wt, v0, P);
        reduce_squash<128><<<dim3(64), dim3(256), 0, stream>>>(P, v0, vs);   // vs = v0+v1

        caps_stream4<false><<<dim3(1024), dim3(256), 0, stream>>>(x, Wt, vs, P);
        reduce_squash<128><<<dim3(64), dim3(256), 0, stream>>>(P, nullptr, out);
    } else if (ws_size >= NEED2) {
        // T2: proven R6 LDS path
        float* P  = (float*)d_ws;
        float* v0 = P + P1;
        float* vs = v0 + 65536;

        caps_pass<16, true, false><<<dim3(1024), dim3(256), 0, stream>>>(x, W, nullptr, P);
        reduce_squash<128><<<dim3(64), dim3(256), 0, stream>>>(P, nullptr, v0);

        caps_pass<16, false, false><<<dim3(1024), dim3(256), 0, stream>>>(x, W, v0, P);
        reduce_squash<128><<<dim3(64), dim3(256), 0, stream>>>(P, v0, vs);

        caps_pass<16, false, false><<<dim3(1024), dim3(256), 0, stream>>>(x, W, vs, P);
        reduce_squash<128><<<dim3(64), dim3(256), 0, stream>>>(P, nullptr, out);
    } else {
        // T3: atomic fallback
        float* s  = (float*)d_ws;
        float* v0 = s + 65536;
        float* vs = v0 + 65536;
        const size_t sbytes = (size_t)65536 * sizeof(float);

        hipMemsetAsync(s, 0, sbytes, stream);
        caps_pass<16, true, true><<<dim3(1024), dim3(256), 0, stream>>>(x, W, nullptr, s);
        squash_k<<<dim3(16), dim3(256), 0, stream>>>(s, nullptr, v0);

        hipMemsetAsync(s, 0, sbytes, stream);
        caps_pass<16, false, true><<<dim3(1024), dim3(256), 0, stream>>>(x, W, v0, s);
        squash_k<<<dim3(16), dim3(256), 0, stream>>>(s, v0, vs);

        hipMemsetAsync(s, 0, sbytes, stream);
        caps_pass<16, false, true><<<dim3(1024), dim3(256), 0, stream>>>(x, W, vs, s);
        squash_k<<<dim3(16), dim3(256), 0, stream>>>(s, nullptr, out);
    }
}